// Round 2
// baseline (62.043 us; speedup 1.0000x reference)
//
#include <hip/hip_runtime.h>

// Shapes fixed by the reference: B=1, S=4096, H=32, D=128, M=4096.
#define HH 32
#define DD 128
#define MM 4096
#define ROW_F4 1024          // H*D/4 float4 per token row
#define D_F4   32            // D/4 float4 per (h, m) row

typedef float v4f __attribute__((ext_vector_type(4)));

// One phase: load 4 x v4f of one tensor (k or v) for token s into registers,
// block-amax, scale, quantize from registers, nontemporal-store to [H,M,D].
__device__ __forceinline__ void quant_phase(const v4f* __restrict__ src_row,  // token row base, f4 units
                                            v4f* __restrict__ dst,            // cache out base, f4 units
                                            float* __restrict__ scbase,       // scales out [H][M]
                                            int m, int t, float div,
                                            volatile float* red)              // 4 floats LDS
{
    v4f a[4];
    float am = 0.0f;
    #pragma unroll
    for (int c = 0; c < 4; ++c) {
        a[c] = src_row[c * 256 + t];
        am = fmaxf(am, fmaxf(fmaxf(fabsf(a[c].x), fabsf(a[c].y)),
                             fmaxf(fabsf(a[c].z), fabsf(a[c].w))));
    }
    #pragma unroll
    for (int off = 32; off > 0; off >>= 1)
        am = fmaxf(am, __shfl_xor(am, off, 64));
    if ((t & 63) == 0) red[t >> 6] = am;
    __syncthreads();
    am = fmaxf(fmaxf(red[0], red[1]), fmaxf(red[2], red[3]));

    const float s = fmaxf(am / div, 1e-8f);
    const float r = 1.0f / s;       // correctly-rounded recip: <=1ulp vs div

    #pragma unroll
    for (int c = 0; c < 4; ++c) {
        int f4 = c * 256 + t;
        int o  = (f4 >> 5) * (MM * D_F4) + m * D_F4 + (f4 & 31);
        v4f q;
        q.x = fminf(fmaxf(a[c].x * r, -448.0f), 448.0f);
        q.y = fminf(fmaxf(a[c].y * r, -448.0f), 448.0f);
        q.z = fminf(fmaxf(a[c].z * r, -448.0f), 448.0f);
        q.w = fminf(fmaxf(a[c].w * r, -448.0f), 448.0f);
        __builtin_nontemporal_store(q, dst + o);
    }
    if (t < HH) __builtin_nontemporal_store(s, scbase + t * MM + m);
}

__global__ __launch_bounds__(256)
void teleport_quant_kernel(const float* __restrict__ kin,
                           const float* __restrict__ vin,
                           const float* __restrict__ unc,
                           const float* __restrict__ kc_in,
                           const float* __restrict__ vc_in,
                           const float* __restrict__ ksc_in,
                           const float* __restrict__ vsc_in,
                           const int*   __restrict__ cur_pos,
                           float* __restrict__ kc_out,
                           float* __restrict__ vc_out,
                           float* __restrict__ ksc_out,
                           float* __restrict__ vsc_out,
                           int S)
{
    const int m = blockIdx.x;      // output cache position 0..M-1
    const int t = threadIdx.x;     // 0..255

    // Inverse circular map: which token (if any) last wrote position m.
    int cp  = *cur_pos;
    int cpm = cp % MM; if (cpm < 0) cpm += MM;
    int s0  = m - cpm; if (s0 < 0) s0 += MM;
    const int s = (s0 < S) ? (s0 + MM * ((S - 1 - s0) / MM)) : -1;

    if (s < 0) {
        // Position untouched this step: copy old cache + scales through.
        const v4f* kci = reinterpret_cast<const v4f*>(kc_in);
        const v4f* vci = reinterpret_cast<const v4f*>(vc_in);
        v4f* kco = reinterpret_cast<v4f*>(kc_out);
        v4f* vco = reinterpret_cast<v4f*>(vc_out);
        #pragma unroll
        for (int c = 0; c < 4; ++c) {
            int f4 = c * 256 + t;
            int o  = (f4 >> 5) * (MM * D_F4) + m * D_F4 + (f4 & 31);
            __builtin_nontemporal_store(kci[o], kco + o);
            __builtin_nontemporal_store(vci[o], vco + o);
        }
        if (t < HH)          __builtin_nontemporal_store(ksc_in[t * MM + m], ksc_out + t * MM + m);
        else if (t < 2 * HH) __builtin_nontemporal_store(vsc_in[(t - HH) * MM + m], vsc_out + (t - HH) * MM + m);
        return;
    }

    __shared__ float red[8];   // [0..3] K-phase, [4..7] V-phase
    const float u   = unc[s];
    const float div = (u > 0.1f) ? 224.0f : 448.0f;

    quant_phase(reinterpret_cast<const v4f*>(kin) + (size_t)s * ROW_F4,
                reinterpret_cast<v4f*>(kc_out), ksc_out, m, t, div, red);
    quant_phase(reinterpret_cast<const v4f*>(vin) + (size_t)s * ROW_F4,
                reinterpret_cast<v4f*>(vc_out), vsc_out, m, t, div, red + 4);
}

extern "C" void kernel_launch(void* const* d_in, const int* in_sizes, int n_in,
                              void* d_out, int out_size, void* d_ws, size_t ws_size,
                              hipStream_t stream) {
    const float* kin = (const float*)d_in[0];
    const float* vin = (const float*)d_in[1];
    const float* unc = (const float*)d_in[2];
    const float* kc  = (const float*)d_in[3];
    const float* vc  = (const float*)d_in[4];
    const float* ksc = (const float*)d_in[5];
    const float* vsc = (const float*)d_in[6];
    const int*   cp  = (const int*)d_in[7];
    const int S = in_sizes[2];   // B*S with B=1

    float* out  = (float*)d_out;
    float* kco  = out;
    float* vco  = kco + (size_t)HH * MM * DD;
    float* ksco = vco + (size_t)HH * MM * DD;
    float* vsco = ksco + (size_t)HH * MM;

    teleport_quant_kernel<<<MM, 256, 0, stream>>>(
        kin, vin, unc, kc, vc, ksc, vsc, cp, kco, vco, ksco, vsco, S);
}

// Round 3
// 50.008 us; speedup vs baseline: 1.2407x; 1.2407x over previous
//
#include <hip/hip_runtime.h>

// Shapes fixed by the reference: B=1, S=4096, H=32, D=128, M=4096.
#define HH 32
#define DD 128
#define MM 4096
#define ROW_F4 1024          // H*D/4 float4 per token row
#define D_F4   32            // D/4 float4 per (h, m) row

typedef float v4f __attribute__((ext_vector_type(4)));

__global__ __launch_bounds__(256)
void teleport_quant_kernel(const float* __restrict__ kin,
                           const float* __restrict__ vin,
                           const float* __restrict__ unc,
                           const float* __restrict__ kc_in,
                           const float* __restrict__ vc_in,
                           const float* __restrict__ ksc_in,
                           const float* __restrict__ vsc_in,
                           const int*   __restrict__ cur_pos,
                           float* __restrict__ kc_out,
                           float* __restrict__ vc_out,
                           float* __restrict__ ksc_out,
                           float* __restrict__ vsc_out,
                           int S)
{
    const int m = blockIdx.x;      // output cache position 0..M-1
    const int t = threadIdx.x;     // 0..255

    // Inverse circular map: which token (if any) last wrote position m.
    int cp  = *cur_pos;
    int cpm = cp % MM; if (cpm < 0) cpm += MM;
    int s0  = m - cpm; if (s0 < 0) s0 += MM;
    const int s = (s0 < S) ? (s0 + MM * ((S - 1 - s0) / MM)) : -1;

    if (s < 0) {
        // Position untouched this step: copy old cache + scales through.
        const v4f* kci = reinterpret_cast<const v4f*>(kc_in);
        const v4f* vci = reinterpret_cast<const v4f*>(vc_in);
        v4f* kco = reinterpret_cast<v4f*>(kc_out);
        v4f* vco = reinterpret_cast<v4f*>(vc_out);
        #pragma unroll
        for (int c = 0; c < 4; ++c) {
            int f4 = c * 256 + t;
            int o  = (f4 >> 5) * (MM * D_F4) + m * D_F4 + (f4 & 31);
            kco[o] = kci[o];
            vco[o] = vci[o];
        }
        if (t < HH)          ksc_out[t * MM + m]        = ksc_in[t * MM + m];
        else if (t < 2 * HH) vsc_out[(t - HH) * MM + m] = vsc_in[(t - HH) * MM + m];
        return;
    }

    // ---- quantize token s into cache position m ----
    const v4f* k4 = reinterpret_cast<const v4f*>(kin) + (size_t)s * ROW_F4;
    const v4f* v4 = reinterpret_cast<const v4f*>(vin) + (size_t)s * ROW_F4;

    v4f ka[4], va[4];
    float amk = 0.0f, amv = 0.0f;
    #pragma unroll
    for (int c = 0; c < 4; ++c) {
        int f4 = c * 256 + t;
        ka[c] = k4[f4];
        va[c] = v4[f4];
        amk = fmaxf(amk, fmaxf(fmaxf(fabsf(ka[c].x), fabsf(ka[c].y)),
                               fmaxf(fabsf(ka[c].z), fabsf(ka[c].w))));
        amv = fmaxf(amv, fmaxf(fmaxf(fabsf(va[c].x), fabsf(va[c].y)),
                               fmaxf(fabsf(va[c].z), fabsf(va[c].w))));
    }

    // wave64 butterfly reduce (both values)
    #pragma unroll
    for (int off = 32; off > 0; off >>= 1) {
        amk = fmaxf(amk, __shfl_xor(amk, off, 64));
        amv = fmaxf(amv, __shfl_xor(amv, off, 64));
    }
    __shared__ float rk[4], rv[4];
    const int wid = t >> 6;
    if ((t & 63) == 0) { rk[wid] = amk; rv[wid] = amv; }
    __syncthreads();
    amk = fmaxf(fmaxf(rk[0], rk[1]), fmaxf(rk[2], rk[3]));
    amv = fmaxf(fmaxf(rv[0], rv[1]), fmaxf(rv[2], rv[3]));

    // Pin the staged k/v values in registers: forbid the compiler from
    // rematerializing the global loads after the barrier (R0/R1 showed
    // VGPR_Count=28 -> it was re-loading 8KB/block from L2/L3 here,
    // serializing the store phase behind a second read).
    #pragma unroll
    for (int c = 0; c < 4; ++c) {
        asm volatile("" : "+v"(ka[c]), "+v"(va[c]));
    }

    const float u   = unc[s];
    const float div = (u > 0.1f) ? 224.0f : 448.0f;
    const float ks  = fmaxf(amk / div, 1e-8f);
    const float vs  = fmaxf(amv / div, 1e-8f);
    const float rks = 1.0f / ks;   // correctly-rounded; <=1ulp vs per-elem div
    const float rvs = 1.0f / vs;

    v4f* kco = reinterpret_cast<v4f*>(kc_out);
    v4f* vco = reinterpret_cast<v4f*>(vc_out);
    #pragma unroll
    for (int c = 0; c < 4; ++c) {
        int f4 = c * 256 + t;
        int o  = (f4 >> 5) * (MM * D_F4) + m * D_F4 + (f4 & 31);
        v4f qk, qv;
        qk.x = fminf(fmaxf(ka[c].x * rks, -448.0f), 448.0f);
        qk.y = fminf(fmaxf(ka[c].y * rks, -448.0f), 448.0f);
        qk.z = fminf(fmaxf(ka[c].z * rks, -448.0f), 448.0f);
        qk.w = fminf(fmaxf(ka[c].w * rks, -448.0f), 448.0f);
        qv.x = fminf(fmaxf(va[c].x * rvs, -448.0f), 448.0f);
        qv.y = fminf(fmaxf(va[c].y * rvs, -448.0f), 448.0f);
        qv.z = fminf(fmaxf(va[c].z * rvs, -448.0f), 448.0f);
        qv.w = fminf(fmaxf(va[c].w * rvs, -448.0f), 448.0f);
        kco[o] = qk;
        vco[o] = qv;
    }

    if (t < HH)            ksc_out[t * MM + m]        = ks;
    else if (t < 2 * HH)   vsc_out[(t - HH) * MM + m] = vs;
}

extern "C" void kernel_launch(void* const* d_in, const int* in_sizes, int n_in,
                              void* d_out, int out_size, void* d_ws, size_t ws_size,
                              hipStream_t stream) {
    const float* kin = (const float*)d_in[0];
    const float* vin = (const float*)d_in[1];
    const float* unc = (const float*)d_in[2];
    const float* kc  = (const float*)d_in[3];
    const float* vc  = (const float*)d_in[4];
    const float* ksc = (const float*)d_in[5];
    const float* vsc = (const float*)d_in[6];
    const int*   cp  = (const int*)d_in[7];
    const int S = in_sizes[2];   // B*S with B=1

    float* out  = (float*)d_out;
    float* kco  = out;
    float* vco  = kco + (size_t)HH * MM * DD;
    float* ksco = vco + (size_t)HH * MM * DD;
    float* vsco = ksco + (size_t)HH * MM;

    teleport_quant_kernel<<<MM, 256, 0, stream>>>(
        kin, vin, unc, kc, vc, ksc, vsc, cp, kco, vco, ksco, vsco, S);
}